// Round 14
// baseline (89.564 us; speedup 1.0000x reference)
//
#include <hip/hip_runtime.h>
#include <hip/hip_bf16.h>

typedef __attribute__((ext_vector_type(4)))  int      int4v;
typedef __attribute__((ext_vector_type(16))) int      i32x16;
typedef __attribute__((ext_vector_type(4)))  unsigned uint4v;
typedef __attribute__((ext_vector_type(2)))  unsigned uint2v;

#define K_DIM    4096
#define N_DIM    16384
#define WORDS_N  512
#define XSCALE   24.0f
#define INV_XS   (1.0f / 24.0f)
#define NBLK     512u

// ---- one fused kernel: phase P (transpose+quantize) -> barrier -> phase G ----
__global__ __launch_bounds__(512, 4)
void fused(const unsigned* __restrict__ Bnz,
           const unsigned* __restrict__ Bsg,
           const float* __restrict__ x32,
           const float* __restrict__ bias,
           uint2v* __restrict__ BT2,
           uint4v* __restrict__ xq,
           unsigned* __restrict__ cnt,
           float* __restrict__ out)
{
    __shared__ char shraw[32768];                      // union: prep sm / gemm red
    unsigned (*sm)[32][65] = (unsigned (*)[32][65])shraw;   // [2][32][65] = 16.6 KB
    int (*red)[1024]       = (int (*)[1024])shraw;          // [8][1024]   = 32 KB

    const int bid = blockIdx.x;        // 512 blocks
    const int t   = threadIdx.x;

    // ================= phase P =================
    // x quantize: 16 entries/block (8192 total)
    if (t < 16) {
        const int e   = bid * 16 + t;
        const int bl  = e & 31;
        const int hh  = (e >> 5) & 1;
        const int kbl = e >> 6;                  // 0..127
        const float* src = x32 + (size_t)bl * K_DIM + kbl * 32 + hh * 16;
        uint4v w;
        #pragma unroll
        for (int g = 0; g < 4; ++g) {
            const float4 v = *(const float4*)(src + g * 4);
            const int i0 = __float2int_rn(fminf(fmaxf(v.x * XSCALE, -127.f), 127.f));
            const int i1 = __float2int_rn(fminf(fmaxf(v.y * XSCALE, -127.f), 127.f));
            const int i2 = __float2int_rn(fminf(fmaxf(v.z * XSCALE, -127.f), 127.f));
            const int i3 = __float2int_rn(fminf(fmaxf(v.w * XSCALE, -127.f), 127.f));
            const unsigned p01 = __builtin_amdgcn_perm((unsigned)i1, (unsigned)i0, 0x00000400u);
            const unsigned p23 = __builtin_amdgcn_perm((unsigned)i3, (unsigned)i2, 0x00000400u);
            w[g] = __builtin_amdgcn_perm(p23, p01, 0x05040100u);
        }
        xq[e] = w;
    }

    const int wcp0 = (bid & 7) * 64;   // word-col group == this block's gemm group
    const int lane = t & 63;
    const int wv   = t >> 6;
    const int half = lane >> 5;
    const int j    = lane & 31;

    // Butterfly constants. Steps 1,2,4: keep-mask + rotate; 8,16: single v_perm.
    unsigned msel[3], rr[3];
    #pragma unroll
    for (int st = 0; st < 3; ++st) {
        const int s = 1 << st;
        const unsigned m = (st==0)?0x55555555u:(st==1)?0x33333333u:0x0F0F0F0Fu;
        const unsigned full = (lane & s) ? 0xFFFFFFFFu : 0u;
        msel[st] = m ^ full;
        rr[st]   = (lane & s) ? (unsigned)s : (unsigned)(32 - s);
    }
    const unsigned sel8  = (lane & 8)  ? 0x07030501u : 0x02060004u;
    const unsigned sel16 = (lane & 16) ? 0x07060302u : 0x01000504u;

    auto bfly = [&](unsigned xw) -> unsigned {
        #pragma unroll
        for (int st = 0; st < 3; ++st) {
            unsigned y = __shfl_xor(xw, 1 << st, 64);
            xw = (xw & msel[st]) |
                 (__builtin_amdgcn_alignbit(y, y, rr[st]) & ~msel[st]);
        }
        unsigned y = __shfl_xor(xw, 8, 64);
        xw = __builtin_amdgcn_perm(xw, y, sel8);
        y = __shfl_xor(xw, 16, 64);
        return __builtin_amdgcn_perm(xw, y, sel16);
    };

    // 2 kbl-panels per block: kbl = (bid>>3)*2 + p, for word-cols of this group
    #pragma unroll 1
    for (int p = 0; p < 2; ++p) {
        const int kbl = (bid >> 3) * 2 + p;      // 0..127

        {   // stage 32 k x 64 wc words, both planes, coalesced
            const int r  = t >> 4;               // 0..31
            const int c0 = (t & 15) * 4;
            const unsigned* s0 = Bnz + (size_t)(kbl * 32 + r) * WORDS_N + wcp0 + c0;
            uint4v v0 = *(const uint4v*)s0;
            sm[0][r][c0+0]=v0[0]; sm[0][r][c0+1]=v0[1]; sm[0][r][c0+2]=v0[2]; sm[0][r][c0+3]=v0[3];
            const unsigned* s1 = Bsg + (size_t)(kbl * 32 + r) * WORDS_N + wcp0 + c0;
            uint4v w0 = *(const uint4v*)s1;
            sm[1][r][c0+0]=w0[0]; sm[1][r][c0+1]=w0[1]; sm[1][r][c0+2]=w0[2]; sm[1][r][c0+3]=w0[3];
        }
        __syncthreads();

        #pragma unroll
        for (int i = 0; i < 4; ++i) {
            const int wcl = wv * 8 + half * 4 + i;
            uint2v o;
            o[0] = bfly(sm[0][j][wcl]);          // nz
            o[1] = bfly(sm[1][j][wcl]);          // sg
            const int n = (wcp0 + wcl) * 32 + j;
            BT2[(size_t)kbl * N_DIM + n] = o;
        }
        __syncthreads();
    }

    // ================= device barrier (lightweight) =================
    if (t == 0) {
        __hip_atomic_fetch_add(cnt, 1u, __ATOMIC_RELEASE, __HIP_MEMORY_SCOPE_AGENT);
        while (__hip_atomic_load(cnt, __ATOMIC_RELAXED, __HIP_MEMORY_SCOPE_AGENT) < NBLK)
            __builtin_amdgcn_s_sleep(2);
    }
    __syncthreads();
    __builtin_amdgcn_fence(__ATOMIC_ACQUIRE, "agent");

    // ================= phase G =================
    const int wc = wcp0 + (bid >> 3);            // one word-column per block
    const int n0 = wc * 32;
    const int h  = half;
    const int bl = j;

    const uint2v* bp = BT2 + (size_t)(wv * 16) * N_DIM + n0 + bl;
    const int kblk0 = wv * 16;                   // wave owns 16 kbl = 512 k

    i32x16 acc{};
    uint2v cb0, cb1;

    cb0 = bp[0];
    cb1 = bp[(size_t)1 * N_DIM];

    const unsigned M = 0x00204081u, K1 = 0x01010101u, P = 0xFF000100u;
    auto dec16 = [&](unsigned nzw, unsigned sgw, unsigned out[4]) {
        #pragma unroll
        for (int g = 0; g < 4; ++g) {
            const unsigned tt = (((nzw >> (h * 16 + 4 * g)) & 0xFu) * M) & K1;
            const unsigned uu = (((sgw >> (h * 16 + 4 * g)) & 0xFu) * M) & K1;
            out[g] = __builtin_amdgcn_perm(P, P, tt | (uu << 1));
        }
    };

    #pragma unroll
    for (int c = 0; c < 8; ++c) {
        uint2v pb0{}, pb1{};
        if (c + 1 < 8) {                         // issue next-chunk B loads early
            pb0 = bp[(size_t)(2 * c + 2) * N_DIM];
            pb1 = bp[(size_t)(2 * c + 3) * N_DIM];
        }
        const int ke = kblk0 + 2 * c;
        int4v cae = ((const int4v*)xq)[((ke + 0) * 2 + h) * 32 + bl];
        int4v cao = ((const int4v*)xq)[((ke + 1) * 2 + h) * 32 + bl];

        union { unsigned u[4]; int4v v; } bb;
        dec16(cb0[0], cb0[1], bb.u);
        acc = __builtin_amdgcn_mfma_i32_32x32x32_i8(cae, bb.v, acc, 0, 0, 0);
        dec16(cb1[0], cb1[1], bb.u);
        acc = __builtin_amdgcn_mfma_i32_32x32x32_i8(cao, bb.v, acc, 0, 0, 0);

        cb0 = pb0; cb1 = pb1;
    }

    // Per-wave partial tile -> LDS (i32, exact).
    // C/D layout: col = lane&31, row = (r&3) + 8*(r>>2) + 4*(lane>>5)
    #pragma unroll
    for (int r = 0; r < 16; ++r) {
        const int row = (r & 3) + 8 * (r >> 2) + 4 * h;
        red[wv][row * 32 + bl] = acc[r];
    }
    __syncthreads();

    // 8-way K reduction (exact i32) + scale + bias + ReLU + fp32 store.
    const int i0 = t * 2;
    int sx = 0, sy = 0;
    #pragma unroll
    for (int s = 0; s < 8; ++s) {
        const int2 pr = *(const int2*)&red[s][i0];
        sx += pr.x;
        sy += pr.y;
    }
    const int m  = t >> 4;              // output row 0..31
    const int nn = i0 & 31;             // even column within tile
    const float2 bv = *(const float2*)(bias + n0 + nn);
    float2 y;
    y.x = (float)sx * INV_XS + bv.x; y.x = y.x < 0.f ? 0.f : y.x;
    y.y = (float)sy * INV_XS + bv.y; y.y = y.y < 0.f ? 0.f : y.y;
    *(float2*)(out + (size_t)m * N_DIM + n0 + nn) = y;
}

extern "C" void kernel_launch(void* const* d_in, const int* in_sizes, int n_in,
                              void* d_out, int out_size, void* d_ws, size_t ws_size,
                              hipStream_t stream) {
    const unsigned* nz  = (const unsigned*)d_in[1];
    const unsigned* sg  = (const unsigned*)d_in[2];
    const float* x32    = (const float*)d_in[0];      // fp32 [32][4096]
    const float* bias   = (const float*)d_in[3];
    float* out          = (float*)d_out;

    // ws: [0,16M) BT2 ; [16M,16M+128K) xq ; [16M+128K, +64B) barrier counter
    char* ws = (char*)d_ws;
    uint2v*   BT2  = (uint2v*)ws;
    uint4v*   xq   = (uint4v*)(ws + (size_t)16 * 1024 * 1024);
    unsigned* cnt  = (unsigned*)(ws + (size_t)16 * 1024 * 1024 + 128 * 1024);

    hipMemsetAsync(cnt, 0, 64, stream);   // reset barrier (graph-capture-safe node)
    fused<<<512, 512, 0, stream>>>(nz, sg, x32, bias, BT2, xq, cnt, out);
}

// Round 15
// 26.800 us; speedup vs baseline: 3.3419x; 3.3419x over previous
//
#include <hip/hip_runtime.h>
#include <hip/hip_bf16.h>

typedef __attribute__((ext_vector_type(4)))  int      int4v;
typedef __attribute__((ext_vector_type(16))) int      i32x16;
typedef __attribute__((ext_vector_type(4)))  unsigned uint4v;
typedef __attribute__((ext_vector_type(2)))  unsigned uint2v;

#define K_DIM    4096
#define N_DIM    16384
#define WORDS_N  512
#define XSCALE   24.0f
#define INV_XS   (1.0f / 24.0f)

// ---------------- P: transpose both planes -> dense BT2 pairs + xq ----------
__global__ __launch_bounds__(512, 4)
void prep(const unsigned* __restrict__ Bnz,
          const unsigned* __restrict__ Bsg,
          const float* __restrict__ x32,
          uint2v* __restrict__ BT2,
          uint4v* __restrict__ xq)
{
    __shared__ unsigned sm[2][32][65];   // 16.6 KB

    const int bid = blockIdx.x;          // 1024 = 128 kbl x 8 wcpan
    const int t   = threadIdx.x;

    // x quantize role: 8 entries/block (8192 total)
    if (t < 8) {
        const int e   = bid * 8 + t;
        const int bl  = e & 31;
        const int hh  = (e >> 5) & 1;
        const int kbl = e >> 6;                  // 0..127
        const float* src = x32 + (size_t)bl * K_DIM + kbl * 32 + hh * 16;
        uint4v w;
        #pragma unroll
        for (int g = 0; g < 4; ++g) {
            const float4 v = *(const float4*)(src + g * 4);
            const int i0 = __float2int_rn(fminf(fmaxf(v.x * XSCALE, -127.f), 127.f));
            const int i1 = __float2int_rn(fminf(fmaxf(v.y * XSCALE, -127.f), 127.f));
            const int i2 = __float2int_rn(fminf(fmaxf(v.z * XSCALE, -127.f), 127.f));
            const int i3 = __float2int_rn(fminf(fmaxf(v.w * XSCALE, -127.f), 127.f));
            const unsigned p01 = __builtin_amdgcn_perm((unsigned)i1, (unsigned)i0, 0x00000400u);
            const unsigned p23 = __builtin_amdgcn_perm((unsigned)i3, (unsigned)i2, 0x00000400u);
            w[g] = __builtin_amdgcn_perm(p23, p01, 0x05040100u);
        }
        xq[e] = w;
    }

    const int kbl  = bid >> 3;           // 0..127 (32 k each)
    const int wcp0 = (bid & 7) * 64;     // word-col group == gemm's XCD group

    // stage 32 k x 64 wc words for BOTH planes, coalesced: 4 words/thread/plane
    {
        const int r  = t >> 4;           // 0..31
        const int c0 = (t & 15) * 4;
        const unsigned* s0 = Bnz + (size_t)(kbl * 32 + r) * WORDS_N + wcp0 + c0;
        uint4v v0 = *(const uint4v*)s0;
        sm[0][r][c0+0]=v0[0]; sm[0][r][c0+1]=v0[1]; sm[0][r][c0+2]=v0[2]; sm[0][r][c0+3]=v0[3];
        const unsigned* s1 = Bsg + (size_t)(kbl * 32 + r) * WORDS_N + wcp0 + c0;
        uint4v w0 = *(const uint4v*)s1;
        sm[1][r][c0+0]=w0[0]; sm[1][r][c0+1]=w0[1]; sm[1][r][c0+2]=w0[2]; sm[1][r][c0+3]=w0[3];
    }
    __syncthreads();

    const int lane = t & 63;
    const int wv   = t >> 6;
    const int half = lane >> 5;
    const int j    = lane & 31;

    // Butterfly constants. Steps 1,2,4: keep-mask + rotate; 8,16: single v_perm.
    unsigned msel[3], rr[3];
    #pragma unroll
    for (int st = 0; st < 3; ++st) {
        const int s = 1 << st;
        const unsigned m = (st==0)?0x55555555u:(st==1)?0x33333333u:0x0F0F0F0Fu;
        const unsigned full = (lane & s) ? 0xFFFFFFFFu : 0u;
        msel[st] = m ^ full;
        rr[st]   = (lane & s) ? (unsigned)s : (unsigned)(32 - s);
    }
    const unsigned sel8  = (lane & 8)  ? 0x07030501u : 0x02060004u;
    const unsigned sel16 = (lane & 16) ? 0x07060302u : 0x01000504u;

    auto bfly = [&](unsigned xw) -> unsigned {
        #pragma unroll
        for (int st = 0; st < 3; ++st) {
            unsigned y = __shfl_xor(xw, 1 << st, 64);
            xw = (xw & msel[st]) |
                 (__builtin_amdgcn_alignbit(y, y, rr[st]) & ~msel[st]);
        }
        unsigned y = __shfl_xor(xw, 8, 64);
        xw = __builtin_amdgcn_perm(xw, y, sel8);
        y = __shfl_xor(xw, 16, 64);
        return __builtin_amdgcn_perm(xw, y, sel16);
    };

    // 4 (wcl) tasks/thread x {nz,sg} -> one coalesced dwordx2 store per task
    #pragma unroll
    for (int i = 0; i < 4; ++i) {
        const int wcl = wv * 8 + half * 4 + i;
        uint2v o;
        o[0] = bfly(sm[0][j][wcl]);      // nz
        o[1] = bfly(sm[1][j][wcl]);      // sg
        const int n = (wcp0 + wcl) * 32 + j;
        BT2[(size_t)kbl * N_DIM + n] = o;
    }
}

// ---------------- G: i8 GEMM, 16 waves/block, in-block K-reduce --------------
__device__ __forceinline__ void dec16_i8(unsigned nzw, unsigned sgw, int h,
                                         unsigned out[4]) {
    const unsigned M = 0x00204081u, K1 = 0x01010101u, P = 0xFF000100u;
    #pragma unroll
    for (int g = 0; g < 4; ++g) {
        const unsigned tt = (((nzw >> (h * 16 + 4 * g)) & 0xFu) * M) & K1;
        const unsigned uu = (((sgw >> (h * 16 + 4 * g)) & 0xFu) * M) & K1;
        const unsigned sel = tt | (uu << 1);
        out[g] = __builtin_amdgcn_perm(P, P, sel);
    }
}

__global__ __launch_bounds__(1024, 8)
void gemm_fused(const int4v* __restrict__ xq,
                const uint2v* __restrict__ BT2,
                const float* __restrict__ bias,
                float* __restrict__ out)
{
    __shared__ int red[16][1024];              // 64 KB: 16 partial 32x32 tiles

    const int bid = blockIdx.x;                // 512 blocks, one word-column each
    const int wc  = (bid & 7) * 64 + (bid >> 3);    // XCD = bid&7 = wc>>6
    const int n0  = wc * 32;
    const int tid = threadIdx.x;
    const int lane = tid & 63;
    const int wv   = tid >> 6;                 // 0..15: wave owns 256 k
    const int h    = lane >> 5;
    const int bl   = lane & 31;

    const uint2v* bp = BT2 + (size_t)(wv * 8) * N_DIM + n0 + bl;
    const int kblk0 = wv * 8;

    i32x16 acc{};

    uint2v cb0, cb1;                           // B pair for the 2 kbl of this chunk

    cb0 = bp[0];
    cb1 = bp[(size_t)1 * N_DIM];

    #pragma unroll
    for (int c = 0; c < 4; ++c) {
        uint2v pb0{}, pb1{};
        if (c + 1 < 4) {                       // issue next-chunk B loads early
            pb0 = bp[(size_t)(2 * c + 2) * N_DIM];
            pb1 = bp[(size_t)(2 * c + 3) * N_DIM];
        }
        const int ke = kblk0 + 2 * c;
        int4v cae = xq[((ke + 0) * 2 + h) * 32 + bl];
        int4v cao = xq[((ke + 1) * 2 + h) * 32 + bl];

        union { unsigned u[4]; int4v v; } bb;
        dec16_i8(cb0[0], cb0[1], h, bb.u);
        acc = __builtin_amdgcn_mfma_i32_32x32x32_i8(cae, bb.v, acc, 0, 0, 0);
        dec16_i8(cb1[0], cb1[1], h, bb.u);
        acc = __builtin_amdgcn_mfma_i32_32x32x32_i8(cao, bb.v, acc, 0, 0, 0);

        cb0 = pb0; cb1 = pb1;
    }

    // Per-wave partial tile -> LDS (i32, exact).
    // C/D layout: col = lane&31, row = (r&3) + 8*(r>>2) + 4*(lane>>5)
    #pragma unroll
    for (int r = 0; r < 16; ++r) {
        const int row = (r & 3) + 8 * (r >> 2) + 4 * h;
        red[wv][row * 32 + bl] = acc[r];
    }
    __syncthreads();

    // 16-way K reduction (exact i32) + scale + bias + ReLU + fp32 store.
    int s = 0;
    #pragma unroll
    for (int k = 0; k < 16; ++k)
        s += red[k][tid];
    const int m  = tid >> 5;            // output row 0..31
    const int nn = tid & 31;            // column within tile
    float y = (float)s * INV_XS + bias[n0 + nn];
    y = y < 0.f ? 0.f : y;
    out[(size_t)m * N_DIM + n0 + nn] = y;
}

extern "C" void kernel_launch(void* const* d_in, const int* in_sizes, int n_in,
                              void* d_out, int out_size, void* d_ws, size_t ws_size,
                              hipStream_t stream) {
    const float* x32    = (const float*)d_in[0];      // fp32 [32][4096]
    const unsigned* nz  = (const unsigned*)d_in[1];
    const unsigned* sg  = (const unsigned*)d_in[2];
    const float* bias   = (const float*)d_in[3];
    float* out          = (float*)d_out;

    // ws: [0,16M) BT2 dense pairs ; [16M,+128K) xq (i8 A fragments)
    char* ws = (char*)d_ws;
    uint2v* BT2 = (uint2v*)ws;
    uint4v* xq  = (uint4v*)(ws + (size_t)16 * 1024 * 1024);

    prep<<<1024, 512, 0, stream>>>(nz, sg, x32, BT2, xq);
    // INSTRUMENTATION: gemm launched twice (idempotent — identical output).
    // dur_us delta vs round 12 isolates (launch overhead + gemm time).
    gemm_fused<<<512, 1024, 0, stream>>>((const int4v*)xq, BT2, bias, out);
    gemm_fused<<<512, 1024, 0, stream>>>((const int4v*)xq, BT2, bias, out);
}

// Round 16
// 19.587 us; speedup vs baseline: 4.5727x; 1.3683x over previous
//
#include <hip/hip_runtime.h>
#include <hip/hip_bf16.h>

typedef __attribute__((ext_vector_type(4)))  int      int4v;
typedef __attribute__((ext_vector_type(16))) int      i32x16;
typedef __attribute__((ext_vector_type(4)))  unsigned uint4v;

#define K_DIM    4096
#define N_DIM    16384
#define WORDS_N  512
#define XSCALE   24.0f
#define INV_XS   (1.0f / 24.0f)

// ---------------- P: transpose both planes -> BTnz/BTsg + quantize x --------
// Each thread transposes one 8-row slab (rows 8a..8a+7) of one 32x32 bit tile:
// levels 1,2,4 are register-local masked swaps; levels 8,16 are byte-moves done
// with shfl_xor(1|2) + v_perm (selectors identical to the verified 5-shfl form).
__global__ __launch_bounds__(512, 4)
void prep(const unsigned* __restrict__ Bnz,
          const unsigned* __restrict__ Bsg,
          const float* __restrict__ x32,
          unsigned* __restrict__ BTnz,
          unsigned* __restrict__ BTsg,
          uint4v* __restrict__ xq)
{
    __shared__ unsigned sm[2][32][65];   // 16.6 KB

    const int bid = blockIdx.x;          // 1024 = 128 kbl x 8 wcpan
    const int t   = threadIdx.x;

    // x quantize role: 8 entries/block (8192 total)
    if (t < 8) {
        const int e   = bid * 8 + t;
        const int bl  = e & 31;
        const int hh  = (e >> 5) & 1;
        const int kb  = e >> 6;                  // 0..127
        const float* src = x32 + (size_t)bl * K_DIM + kb * 32 + hh * 16;
        uint4v w;
        #pragma unroll
        for (int g = 0; g < 4; ++g) {
            const float4 v = *(const float4*)(src + g * 4);
            const int i0 = __float2int_rn(fminf(fmaxf(v.x * XSCALE, -127.f), 127.f));
            const int i1 = __float2int_rn(fminf(fmaxf(v.y * XSCALE, -127.f), 127.f));
            const int i2 = __float2int_rn(fminf(fmaxf(v.z * XSCALE, -127.f), 127.f));
            const int i3 = __float2int_rn(fminf(fmaxf(v.w * XSCALE, -127.f), 127.f));
            const unsigned p01 = __builtin_amdgcn_perm((unsigned)i1, (unsigned)i0, 0x00000400u);
            const unsigned p23 = __builtin_amdgcn_perm((unsigned)i3, (unsigned)i2, 0x00000400u);
            w[g] = __builtin_amdgcn_perm(p23, p01, 0x05040100u);
        }
        xq[e] = w;
    }

    const int kbl  = bid >> 3;           // 0..127 (32 k each)
    const int wcp0 = (bid & 7) * 64;     // word-col group == gemm's XCD group

    // stage 32 k x 64 wc words for BOTH planes, coalesced: 4 words/thread/plane
    {
        const int r  = t >> 4;           // 0..31
        const int c0 = (t & 15) * 4;
        const unsigned* s0 = Bnz + (size_t)(kbl * 32 + r) * WORDS_N + wcp0 + c0;
        uint4v v0 = *(const uint4v*)s0;
        sm[0][r][c0+0]=v0[0]; sm[0][r][c0+1]=v0[1]; sm[0][r][c0+2]=v0[2]; sm[0][r][c0+3]=v0[3];
        const unsigned* s1 = Bsg + (size_t)(kbl * 32 + r) * WORDS_N + wcp0 + c0;
        uint4v w0 = *(const uint4v*)s1;
        sm[1][r][c0+0]=w0[0]; sm[1][r][c0+1]=w0[1]; sm[1][r][c0+2]=w0[2]; sm[1][r][c0+3]=w0[3];
    }
    __syncthreads();

    const int lane = t & 63;
    const int wv   = t >> 6;             // 0..7
    const int a    = lane & 3;           // row-slab within tile (rows 8a..8a+7)
    const int g    = lane >> 2;          // 0..15
    const int pl   = wv >> 2;            // plane: waves 0-3 nz, 4-7 sg
    const int wcl  = (wv & 3) * 16 + g;  // 0..63

    unsigned w[8];
    #pragma unroll
    for (int i = 0; i < 8; ++i)
        w[i] = sm[pl][8 * a + i][wcl];

    // levels 1,2,4: register-local masked swaps (XOR trick, 6 VALU/pair)
    #pragma unroll
    for (int st = 0; st < 3; ++st) {
        const int s = 1 << st;
        const unsigned nm = (st == 0) ? 0xAAAAAAAAu :
                            (st == 1) ? 0xCCCCCCCCu : 0xF0F0F0F0u;  // ~m
        #pragma unroll
        for (int i = 0; i < 8; ++i) {
            if (i & s) continue;
            const unsigned lo = w[i], hi = w[i + s];
            const unsigned tt = (lo ^ (hi << s)) & nm;
            w[i]     = lo ^ tt;
            w[i + s] = hi ^ (tt >> s);
        }
    }

    // levels 8,16: byte/halfword moves via shfl_xor(1|2) + v_perm.
    // Side keyed on row bits: (r&8)=a&1, (r&16)=a&2. Selector bytes are the
    // same verified constants as the original lane&8/lane&16 butterfly.
    const unsigned sel8  = (a & 1) ? 0x07030501u : 0x02060004u;
    const unsigned sel16 = (a & 2) ? 0x07060302u : 0x01000504u;
    #pragma unroll
    for (int i = 0; i < 8; ++i) {
        unsigned y = __shfl_xor(w[i], 1, 64);
        w[i] = __builtin_amdgcn_perm(w[i], y, sel8);
        y = __shfl_xor(w[i], 2, 64);
        w[i] = __builtin_amdgcn_perm(w[i], y, sel16);
    }

    // w[i] = transposed word for column n = wcl*32 + 8a + i -> contiguous x4 stores
    unsigned* dst = (pl ? BTsg : BTnz) +
                    (size_t)kbl * N_DIM + (wcp0 + wcl) * 32 + 8 * a;
    uint4v o0, o1;
    o0[0]=w[0]; o0[1]=w[1]; o0[2]=w[2]; o0[3]=w[3];
    o1[0]=w[4]; o1[1]=w[5]; o1[2]=w[6]; o1[3]=w[7];
    *(uint4v*)dst       = o0;
    *(uint4v*)(dst + 4) = o1;
}

// ---------------- G: i8 GEMM, 16 waves/block, in-block K-reduce --------------
__device__ __forceinline__ void dec16_i8(unsigned nzw, unsigned sgw, int h,
                                         unsigned out[4]) {
    const unsigned M = 0x00204081u, K1 = 0x01010101u, P = 0xFF000100u;
    #pragma unroll
    for (int g = 0; g < 4; ++g) {
        const unsigned tt = (((nzw >> (h * 16 + 4 * g)) & 0xFu) * M) & K1;
        const unsigned uu = (((sgw >> (h * 16 + 4 * g)) & 0xFu) * M) & K1;
        const unsigned sel = tt | (uu << 1);
        out[g] = __builtin_amdgcn_perm(P, P, sel);
    }
}

__global__ __launch_bounds__(1024, 8)
void gemm_fused(const int4v* __restrict__ xq,
                const unsigned* __restrict__ BTnz,
                const unsigned* __restrict__ BTsg,
                const float* __restrict__ bias,
                float* __restrict__ out)
{
    __shared__ int red[16][1024];              // 64 KB: 16 partial 32x32 tiles

    const int bid = blockIdx.x;                // 512 blocks, one word-column each
    const int wc  = (bid & 7) * 64 + (bid >> 3);    // XCD = bid&7 = wc>>6
    const int n0  = wc * 32;
    const int tid = threadIdx.x;
    const int lane = tid & 63;
    const int wv   = tid >> 6;                 // 0..15: wave owns 256 k
    const int h    = lane >> 5;
    const int bl   = lane & 31;

    const unsigned* np = BTnz + (size_t)(wv * 8) * N_DIM + n0 + bl;
    const unsigned* sp = BTsg + (size_t)(wv * 8) * N_DIM + n0 + bl;
    const int kblk0 = wv * 8;

    i32x16 acc{};

    unsigned cn0, cn1, cs0, cs1;               // {nz,sg} for the 2 kbl of chunk

    cn0 = np[0];
    cn1 = np[(size_t)1 * N_DIM];
    cs0 = sp[0];
    cs1 = sp[(size_t)1 * N_DIM];

    #pragma unroll
    for (int c = 0; c < 4; ++c) {
        unsigned pn0 = 0, pn1 = 0, ps0 = 0, ps1 = 0;
        if (c + 1 < 4) {                       // issue next-chunk B loads early
            pn0 = np[(size_t)(2 * c + 2) * N_DIM];
            pn1 = np[(size_t)(2 * c + 3) * N_DIM];
            ps0 = sp[(size_t)(2 * c + 2) * N_DIM];
            ps1 = sp[(size_t)(2 * c + 3) * N_DIM];
        }
        const int ke = kblk0 + 2 * c;
        int4v cae = xq[((ke + 0) * 2 + h) * 32 + bl];
        int4v cao = xq[((ke + 1) * 2 + h) * 32 + bl];

        union { unsigned u[4]; int4v v; } bb;
        dec16_i8(cn0, cs0, h, bb.u);
        acc = __builtin_amdgcn_mfma_i32_32x32x32_i8(cae, bb.v, acc, 0, 0, 0);
        dec16_i8(cn1, cs1, h, bb.u);
        acc = __builtin_amdgcn_mfma_i32_32x32x32_i8(cao, bb.v, acc, 0, 0, 0);

        cn0 = pn0; cn1 = pn1; cs0 = ps0; cs1 = ps1;
    }

    // Per-wave partial tile -> LDS (i32, exact).
    // C/D layout: col = lane&31, row = (r&3) + 8*(r>>2) + 4*(lane>>5)
    #pragma unroll
    for (int r = 0; r < 16; ++r) {
        const int row = (r & 3) + 8 * (r >> 2) + 4 * h;
        red[wv][row * 32 + bl] = acc[r];
    }
    __syncthreads();

    // 16-way K reduction (exact i32) + scale + bias + ReLU + fp32 store.
    int s = 0;
    #pragma unroll
    for (int k = 0; k < 16; ++k)
        s += red[k][tid];
    const int m  = tid >> 5;            // output row 0..31
    const int nn = tid & 31;            // column within tile
    float y = (float)s * INV_XS + bias[n0 + nn];
    y = y < 0.f ? 0.f : y;
    out[(size_t)m * N_DIM + n0 + nn] = y;
}

extern "C" void kernel_launch(void* const* d_in, const int* in_sizes, int n_in,
                              void* d_out, int out_size, void* d_ws, size_t ws_size,
                              hipStream_t stream) {
    const float* x32    = (const float*)d_in[0];      // fp32 [32][4096]
    const unsigned* nz  = (const unsigned*)d_in[1];
    const unsigned* sg  = (const unsigned*)d_in[2];
    const float* bias   = (const float*)d_in[3];
    float* out          = (float*)d_out;

    // ws: [0,8M) BTnz ; [8M,16M) BTsg ; [16M,+128K) xq (i8 A fragments)
    char* ws = (char*)d_ws;
    unsigned* BTnz = (unsigned*)ws;
    unsigned* BTsg = (unsigned*)(ws + (size_t)8 * 1024 * 1024);
    uint4v*   xq   = (uint4v*)(ws + (size_t)16 * 1024 * 1024);

    prep<<<1024, 512, 0, stream>>>(nz, sg, x32, BTnz, BTsg, xq);
    gemm_fused<<<512, 1024, 0, stream>>>((const int4v*)xq, BTnz, BTsg, bias, out);
}